// Round 9
// baseline (101.178 us; speedup 1.0000x reference)
//
#include <hip/hip_runtime.h>
#include <hip/hip_bf16.h>
#include <cstdint>
#include <cstddef>

#define N_NODES 8192
#define F_IN 512
#define F_OUT 64
#define LOG2E 1.44269504f

#define JSPLIT 8
#define JPB (N_NODES / JSPLIT)   // 1024 j per block
#define JC 256                   // j per staged chunk (32 KB LDS whtf)
#define NCHUNK (JPB / JC)        // 4

typedef __attribute__((ext_vector_type(8))) short short8v;  // 8 bf16 = 4 VGPRs
typedef __attribute__((ext_vector_type(4))) float f32x4;
typedef __attribute__((ext_vector_type(4))) int i32x4;
typedef __attribute__((ext_vector_type(4))) unsigned int u32x4;

static __device__ __forceinline__ unsigned short f2bf(float f) {
    union { float f; unsigned u; } v; v.f = f;
    unsigned u = v.u + 0x7FFFu + ((v.u >> 16) & 1u);   // RNE
    return (unsigned short)(u >> 16);
}
static __device__ __forceinline__ float bf2f(unsigned short b) {
    union { unsigned u; float f; } v; v.u = ((unsigned)b) << 16;
    return v.f;
}
static __device__ __forceinline__ unsigned cvt_pk_bf16(float lo, float hi) {
    unsigned r;
    asm("v_cvt_pk_bf16_f32 %0, %1, %2" : "=v"(r) : "v"(lo), "v"(hi));
    return r;
}

// ---------------------------------------------------------------------------
// Kernel 0: W (512x64 f32) -> fragment-ordered bf16 hi/lo buffers.
// ---------------------------------------------------------------------------
__global__ __launch_bounds__(256)
void gat_wconv(const float* __restrict__ W, unsigned short* __restrict__ whf,
               unsigned short* __restrict__ wlf) {
    const int t = blockIdx.x * 256 + threadIdx.x;   // 0..4095
    const int tile = t >> 6, lane = t & 63;
    const int kt = tile >> 2, ct = tile & 3;
    const int k0 = kt * 32 + ((lane >> 4) << 3);
    const int c  = ct * 16 + (lane & 15);
    short8v h, l;
    #pragma unroll
    for (int i = 0; i < 8; ++i) {
        float v = W[(size_t)(k0 + i) * F_OUT + c];
        unsigned short hb = f2bf(v);
        h[i] = (short)hb;
        l[i] = (short)f2bf(v - bf2f(hb));
    }
    const size_t dst = (size_t)tile * 512 + (size_t)lane * 8;
    *(short8v*)(whf + dst) = h;
    *(short8v*)(wlf + dst) = l;
}

// ---------------------------------------------------------------------------
// Kernel 1: Wh = x@W via bf16 hi/lo split MFMA; s1/s2 (exp2 domain);
// k-permuted whtf:
//   whtf[jb*8192 + q*2048 + ct*512 + lane*8 + i]
//     = bf16(Wh[jb*128 + (lane>>4)*32 + q*8 + i][ct*16 + (lane&15)])
// ---------------------------------------------------------------------------
__global__ __launch_bounds__(256)
void gat_prep(const float* __restrict__ x, const unsigned short* __restrict__ whf,
              const unsigned short* __restrict__ wlf, const float* __restrict__ a,
              unsigned short* __restrict__ whtf,
              float* __restrict__ s1, float* __restrict__ s2) {
    __shared__ f32x4 red[2][4][64];           // 8 KB K-half partials
    __shared__ unsigned short ldsT[64][40];   // [col][row], 80B rows
    const int tid = threadIdx.x;
    const int lane = tid & 63;
    const int wv = tid >> 6;                  // 0..3
    const int rt = wv & 1;                    // row-tile
    const int kh = wv >> 1;                   // K-half
    const int l15 = lane & 15, g = lane >> 4;
    const int jt = blockIdx.x;                // jtile 0..255 (32 Wh-rows each)
    const int row0 = jt * 32 + rt * 16;

    f32x4 acc[4] = {{0.f,0.f,0.f,0.f},{0.f,0.f,0.f,0.f},{0.f,0.f,0.f,0.f},{0.f,0.f,0.f,0.f}};

    const float* xp = x + (size_t)(row0 + l15) * F_IN + kh * 256 + g * 8;
    float4 v[16];
    #pragma unroll
    for (int q = 0; q < 8; ++q) {
        v[2 * q]     = *(const float4*)(xp + q * 32);
        v[2 * q + 1] = *(const float4*)(xp + q * 32 + 4);
    }
    #pragma unroll
    for (int q = 0; q < 8; ++q) {
        const int kt = kh * 8 + q;
        float vv[8] = {v[2*q].x, v[2*q].y, v[2*q].z, v[2*q].w,
                       v[2*q+1].x, v[2*q+1].y, v[2*q+1].z, v[2*q+1].w};
        short8v xh, xl;
        #pragma unroll
        for (int i = 0; i < 8; ++i) {
            unsigned short hb = f2bf(vv[i]);
            xh[i] = (short)hb;
            xl[i] = (short)f2bf(vv[i] - bf2f(hb));
        }
        const unsigned short* wp = whf + (size_t)(kt * 4) * 512 + (size_t)lane * 8;
        const unsigned short* lp = wlf + (size_t)(kt * 4) * 512 + (size_t)lane * 8;
        #pragma unroll
        for (int ct = 0; ct < 4; ++ct) {
            short8v wh = *(const short8v*)(wp + ct * 512);
            short8v wl = *(const short8v*)(lp + ct * 512);
            acc[ct] = __builtin_amdgcn_mfma_f32_16x16x32_bf16(xh, wh, acc[ct], 0, 0, 0);
            acc[ct] = __builtin_amdgcn_mfma_f32_16x16x32_bf16(xl, wh, acc[ct], 0, 0, 0);
            acc[ct] = __builtin_amdgcn_mfma_f32_16x16x32_bf16(xh, wl, acc[ct], 0, 0, 0);
        }
    }

    if (kh == 1) {
        #pragma unroll
        for (int ct = 0; ct < 4; ++ct) red[rt][ct][lane] = acc[ct];
    }
    __syncthreads();

    if (kh == 0) {
        #pragma unroll
        for (int ct = 0; ct < 4; ++ct) acc[ct] += red[rt][ct][lane];

        // s1/s2 (scaled by log2e): C-frag col = ct*16+l15, local row = 4g+r
        #pragma unroll
        for (int r = 0; r < 4; ++r) {
            float p1 = 0.f, p2 = 0.f;
            #pragma unroll
            for (int ct = 0; ct < 4; ++ct) {
                p1 = fmaf(acc[ct][r], a[ct * 16 + l15], p1);
                p2 = fmaf(acc[ct][r], a[64 + ct * 16 + l15], p2);
            }
            p1 += __shfl_xor(p1, 1); p2 += __shfl_xor(p2, 1);
            p1 += __shfl_xor(p1, 2); p2 += __shfl_xor(p2, 2);
            p1 += __shfl_xor(p1, 4); p2 += __shfl_xor(p2, 4);
            p1 += __shfl_xor(p1, 8); p2 += __shfl_xor(p2, 8);
            if (l15 == 0) {
                s1[row0 + g * 4 + r] = p1 * LOG2E;
                s2[row0 + g * 4 + r] = p2 * LOG2E;
            }
        }

        // transpose to [col][row] bf16 in LDS
        #pragma unroll
        for (int ct = 0; ct < 4; ++ct) {
            ushort4 pk;
            pk.x = f2bf(acc[ct][0]); pk.y = f2bf(acc[ct][1]);
            pk.z = f2bf(acc[ct][2]); pk.w = f2bf(acc[ct][3]);
            *(ushort4*)&ldsT[ct * 16 + l15][rt * 16 + g * 4] = pk;
        }
    }
    __syncthreads();

    // emit k-permuted whtf (verified pair with main's consumption in R8)
    {
        const int jb = jt >> 2, gj = jt & 3;
        const int m  = tid >> 6;
        const int ct = (tid >> 4) & 3;
        const int c  = tid & 15;
        short8v sv = *(const short8v*)&ldsT[ct * 16 + c][m * 8];
        *(short8v*)(whtf + (size_t)jb * 8192 + m * 2048 + ct * 512
                         + (size_t)(gj * 16 + c) * 8) = sv;
    }
}

// ---------------------------------------------------------------------------
// Kernel 2: fused masked-softmax attention + PV via bf16 MFMA.
// adj is streamed with FILL-LIKE CONTIGUITY: per chunk, each wave issues 16
// load instructions, each covering one contiguous 1 KB row-segment (lane i
// reads 16 B at base+16i). Lanes pack 4 ints -> 1 nibble-byte into a
// wave-private LDS mask; the MFMA consume path reads u16 -> 8 mask bits.
// whtf chunks LDS-staged double-buffered (R5-proven). Grid 64x8 = 512 blocks.
// ---------------------------------------------------------------------------
__global__ __launch_bounds__(512)
void gat_main(const int* __restrict__ adj, const unsigned short* __restrict__ whtf,
              const float* __restrict__ s1, const float* __restrict__ s2,
              float* __restrict__ numpart, float* __restrict__ denpart) {
    __shared__ unsigned short lds[2][JC * F_OUT];      // 2 x 32 KB whtf
    __shared__ unsigned char mlds[8][16][68];          // per-wave nibble mask (8.5 KB)
    const int tid  = threadIdx.x;
    const int lane = tid & 63;
    const int wv   = tid >> 6;                // 0..7: row-tile within block
    const int l15  = lane & 15, g = lane >> 4;
    const int rg   = blockIdx.x >> 3;         // 0..63 row-group (128 rows)
    const int js   = blockIdx.x & 7;          // j-split (== XCD id)
    const int rowbase = rg * 128 + wv * 16;
    const int row  = rowbase + l15;
    const int j0   = js * JPB;
    const float s1r = s1[row];                // exp2 domain

    const char* gbase = (const char*)whtf + (size_t)j0 * 128;   // 128 B per j col
    const int*  astage = adj + (size_t)rowbase * N_NODES + j0;  // wave's 16 rows
    const float* s2b = s2 + j0 + g * 32;

    f32x4 acc0 = {0.f, 0.f, 0.f, 0.f};
    f32x4 acc1 = acc0, acc2 = acc0, acc3 = acc0;
    float dsum = 0.f;
    i32x4 areg[16];

    #define STAGE(ch, buf) do { \
        const char* _g = gbase + (size_t)(ch) * 32768 + (size_t)tid * 16; \
        char* _l = (char*)&lds[buf][0] + (size_t)wv * 1024; \
        _Pragma("unroll") \
        for (int _i = 0; _i < 4; ++_i) \
            __builtin_amdgcn_global_load_lds( \
                (const __attribute__((address_space(1))) void*)(_g + _i * 8192), \
                (__attribute__((address_space(3))) void*)(_l + _i * 8192), 16, 0, 0); \
    } while (0)

    // one contiguous 1 KB segment per instruction: lane reads 16 B at base+lane*16
    #define LOADA(ch) do { \
        _Pragma("unroll") \
        for (int _r = 0; _r < 16; ++_r) \
            areg[_r] = *(const i32x4*)(astage + (size_t)_r * N_NODES + (ch) * 256 + lane * 4); \
    } while (0)

    #define PACKW() do { \
        _Pragma("unroll") \
        for (int _r = 0; _r < 16; ++_r) { \
            i32x4 _v = areg[_r]; \
            unsigned _nib = ((unsigned)_v[0] & 1u) | (((unsigned)_v[1] & 1u) << 1) \
                          | (((unsigned)_v[2] & 1u) << 2) | (((unsigned)_v[3] & 1u) << 3); \
            mlds[wv][_r][lane] = (unsigned char)_nib; \
        } \
    } while (0)

    STAGE(0, 0);
    LOADA(0);
    __syncthreads();       // drains whtf stage AND adj loads
    PACKW();               // mask for chunk 0 (wave-private)

    for (int ch = 0; ch < NCHUNK; ++ch) {
        const int cur = ch & 1;
        if (ch < NCHUNK - 1) { STAGE(ch + 1, cur ^ 1); LOADA(ch + 1); }

        const unsigned short* lbuf = &lds[cur][0];
        #pragma unroll
        for (int h = 0; h < 2; ++h) {
            const unsigned short* gb = lbuf + h * 8192;
            #pragma unroll
            for (int q = 0; q < 4; ++q) {
                const unsigned short w16 =
                    *(const unsigned short*)&mlds[wv][l15][h * 32 + g * 8 + q * 2];
                const unsigned mb = (w16 & 0xfu) | ((w16 >> 4) & 0xf0u);
                const int jw = (ch * 2 + h) * 128 + q * 8;   // + g*32 in s2b
                float4 sa = *(const float4*)(s2b + jw);
                float4 sb = *(const float4*)(s2b + jw + 4);

                short8v b0 = *(const short8v*)(gb + q * 2048 +    0 + lane * 8);
                short8v b1 = *(const short8v*)(gb + q * 2048 +  512 + lane * 8);
                short8v b2 = *(const short8v*)(gb + q * 2048 + 1024 + lane * 8);
                short8v b3 = *(const short8v*)(gb + q * 2048 + 1536 + lane * 8);

                float w0, w1, w2, w3, w4, w5, w6, w7;
                #define GAT_EL(wvar, bi, s2v) do { \
                    float e = s1r + (s2v); e = fmaxf(e, 0.2f * e); \
                    float ex = __builtin_amdgcn_exp2f(e); \
                    wvar = ((mb >> (bi)) & 1u) ? ex : 0.f; dsum += wvar; } while (0);
                GAT_EL(w0, 0, sa.x) GAT_EL(w1, 1, sa.y)
                GAT_EL(w2, 2, sa.z) GAT_EL(w3, 3, sa.w)
                GAT_EL(w4, 4, sb.x) GAT_EL(w5, 5, sb.y)
                GAT_EL(w6, 6, sb.z) GAT_EL(w7, 7, sb.w)
                #undef GAT_EL

                u32x4 au;
                au[0] = cvt_pk_bf16(w0, w1);
                au[1] = cvt_pk_bf16(w2, w3);
                au[2] = cvt_pk_bf16(w4, w5);
                au[3] = cvt_pk_bf16(w6, w7);
                short8v afrag = __builtin_bit_cast(short8v, au);

                acc0 = __builtin_amdgcn_mfma_f32_16x16x32_bf16(afrag, b0, acc0, 0, 0, 0);
                acc1 = __builtin_amdgcn_mfma_f32_16x16x32_bf16(afrag, b1, acc1, 0, 0, 0);
                acc2 = __builtin_amdgcn_mfma_f32_16x16x32_bf16(afrag, b2, acc2, 0, 0, 0);
                acc3 = __builtin_amdgcn_mfma_f32_16x16x32_bf16(afrag, b3, acc3, 0, 0, 0);
            }
        }
        __syncthreads();   // drains stage+adj loads; fences whtf buffer reuse
        if (ch < NCHUNK - 1) PACKW();   // mask for ch+1 (reads of ch are done)
    }
    #undef STAGE
    #undef LOADA
    #undef PACKW

    // denominator: combine the 4 k-groups (same l15)
    dsum += __shfl_xor(dsum, 16);
    dsum += __shfl_xor(dsum, 32);
    if (lane < 16) denpart[(size_t)js * N_NODES + rowbase + lane] = dsum;

    // partial numerators: C-frag col = l15 (f = ct*16+l15), local row = g*4+r
    float* np = numpart + ((size_t)js * N_NODES + rowbase) * F_OUT;
    #pragma unroll
    for (int r = 0; r < 4; ++r) {
        const int ro = (g * 4 + r) * F_OUT;
        np[ro +  0 + l15] = acc0[r];
        np[ro + 16 + l15] = acc1[r];
        np[ro + 32 + l15] = acc2[r];
        np[ro + 48 + l15] = acc3[r];
    }
}

// ---------------------------------------------------------------------------
// Kernel 3: combine j-split partials, normalize, ELU.
// ---------------------------------------------------------------------------
__global__ __launch_bounds__(256)
void gat_combine(const float* __restrict__ numpart, const float* __restrict__ denpart,
                 float* __restrict__ out) {
    const int idx = blockIdx.x * 256 + threadIdx.x;   // 0..524287
    const int r = idx >> 6;
    float num = 0.f, den = 0.f;
    #pragma unroll
    for (int c = 0; c < JSPLIT; ++c) {
        num += numpart[(size_t)c * N_NODES * F_OUT + idx];
        den += denpart[(size_t)c * N_NODES + r];
    }
    float h = num / den;
    out[idx] = h > 0.f ? h : __expf(h) - 1.f;
}

extern "C" void kernel_launch(void* const* d_in, const int* in_sizes, int n_in,
                              void* d_out, int out_size, void* d_ws, size_t ws_size,
                              hipStream_t stream) {
    const float* x      = (const float*)d_in[0];
    const int*   adj    = (const int*)d_in[1];
    const float* weight = (const float*)d_in[2];
    const float* a      = (const float*)d_in[3];
    float* out = (float*)d_out;

    // ws: whtf 1MB | s1 32KB | s2 32KB | whf 64KB | wlf 64KB | numpart 16MB | denpart 256KB
    char* ws = (char*)d_ws;
    unsigned short* whtf = (unsigned short*)ws;
    float* s1            = (float*)(ws + 1048576);
    float* s2            = (float*)(ws + 1048576 + 32768);
    unsigned short* whf  = (unsigned short*)(ws + 1048576 + 65536);
    unsigned short* wlf  = (unsigned short*)(ws + 1048576 + 131072);
    float* numpart       = (float*)(ws + 1245184);
    float* denpart       = (float*)(ws + 1245184 + 16777216);

    gat_wconv<<<16, 256, 0, stream>>>(weight, whf, wlf);
    gat_prep<<<N_NODES / 32, 256, 0, stream>>>(x, whf, wlf, a, whtf, s1, s2);
    gat_main<<<64 * JSPLIT, 512, 0, stream>>>(adj, whtf, s1, s2, numpart, denpart);
    gat_combine<<<N_NODES * F_OUT / 256, 256, 0, stream>>>(numpart, denpart, out);
}

// Round 10
// 97.994 us; speedup vs baseline: 1.0325x; 1.0325x over previous
//
#include <hip/hip_runtime.h>
#include <hip/hip_bf16.h>
#include <cstdint>
#include <cstddef>

#define N_NODES 8192
#define F_IN 512
#define F_OUT 64
#define LOG2E 1.44269504f

#define JSPLIT 8
#define JPB (N_NODES / JSPLIT)   // 1024 j per block, whole slice LDS-resident

typedef __attribute__((ext_vector_type(8))) short short8v;  // 8 bf16 = 4 VGPRs
typedef __attribute__((ext_vector_type(4))) float f32x4;
typedef __attribute__((ext_vector_type(4))) int i32x4;
typedef __attribute__((ext_vector_type(4))) unsigned int u32x4;

static __device__ __forceinline__ unsigned short f2bf(float f) {
    union { float f; unsigned u; } v; v.f = f;
    unsigned u = v.u + 0x7FFFu + ((v.u >> 16) & 1u);   // RNE
    return (unsigned short)(u >> 16);
}
static __device__ __forceinline__ float bf2f(unsigned short b) {
    union { unsigned u; float f; } v; v.u = ((unsigned)b) << 16;
    return v.f;
}
static __device__ __forceinline__ unsigned cvt_pk_bf16(float lo, float hi) {
    unsigned r;
    asm("v_cvt_pk_bf16_f32 %0, %1, %2" : "=v"(r) : "v"(lo), "v"(hi));
    return r;
}

// ---------------------------------------------------------------------------
// Kernel 0: W (512x64 f32) -> fragment-ordered bf16 hi/lo buffers.
// ---------------------------------------------------------------------------
__global__ __launch_bounds__(256)
void gat_wconv(const float* __restrict__ W, unsigned short* __restrict__ whf,
               unsigned short* __restrict__ wlf) {
    const int t = blockIdx.x * 256 + threadIdx.x;   // 0..4095
    const int tile = t >> 6, lane = t & 63;
    const int kt = tile >> 2, ct = tile & 3;
    const int k0 = kt * 32 + ((lane >> 4) << 3);
    const int c  = ct * 16 + (lane & 15);
    short8v h, l;
    #pragma unroll
    for (int i = 0; i < 8; ++i) {
        float v = W[(size_t)(k0 + i) * F_OUT + c];
        unsigned short hb = f2bf(v);
        h[i] = (short)hb;
        l[i] = (short)f2bf(v - bf2f(hb));
    }
    const size_t dst = (size_t)tile * 512 + (size_t)lane * 8;
    *(short8v*)(whf + dst) = h;
    *(short8v*)(wlf + dst) = l;
}

// ---------------------------------------------------------------------------
// Kernel 1: Wh = x@W via bf16 hi/lo split MFMA, K split 2-way across wave
// pairs. s1/s2 (exp2 domain). R5-proven whtf layout:
// whtf[(jt*4+ft)*512 + lane*8 + i] = bf16(Wh[jt*32 + 8*(lane>>4)+i][ft*16+(lane&15)])
// ---------------------------------------------------------------------------
__global__ __launch_bounds__(256)
void gat_prep(const float* __restrict__ x, const unsigned short* __restrict__ whf,
              const unsigned short* __restrict__ wlf, const float* __restrict__ a,
              unsigned short* __restrict__ whtf,
              float* __restrict__ s1, float* __restrict__ s2) {
    __shared__ f32x4 red[2][4][64];           // 8 KB K-half partials
    __shared__ unsigned short ldsT[64][40];   // [col][row], 80B rows
    const int tid = threadIdx.x;
    const int lane = tid & 63;
    const int wv = tid >> 6;                  // 0..3
    const int rt = wv & 1;                    // row-tile
    const int kh = wv >> 1;                   // K-half
    const int l15 = lane & 15, g = lane >> 4;
    const int jt = blockIdx.x;                // jtile 0..255
    const int row0 = jt * 32 + rt * 16;

    f32x4 acc[4] = {{0.f,0.f,0.f,0.f},{0.f,0.f,0.f,0.f},{0.f,0.f,0.f,0.f},{0.f,0.f,0.f,0.f}};

    const float* xp = x + (size_t)(row0 + l15) * F_IN + kh * 256 + g * 8;
    float4 v[16];
    #pragma unroll
    for (int q = 0; q < 8; ++q) {
        v[2 * q]     = *(const float4*)(xp + q * 32);
        v[2 * q + 1] = *(const float4*)(xp + q * 32 + 4);
    }
    #pragma unroll
    for (int q = 0; q < 8; ++q) {
        const int kt = kh * 8 + q;
        float vv[8] = {v[2*q].x, v[2*q].y, v[2*q].z, v[2*q].w,
                       v[2*q+1].x, v[2*q+1].y, v[2*q+1].z, v[2*q+1].w};
        short8v xh, xl;
        #pragma unroll
        for (int i = 0; i < 8; ++i) {
            unsigned short hb = f2bf(vv[i]);
            xh[i] = (short)hb;
            xl[i] = (short)f2bf(vv[i] - bf2f(hb));
        }
        const unsigned short* wp = whf + (size_t)(kt * 4) * 512 + (size_t)lane * 8;
        const unsigned short* lp = wlf + (size_t)(kt * 4) * 512 + (size_t)lane * 8;
        #pragma unroll
        for (int ct = 0; ct < 4; ++ct) {
            short8v wh = *(const short8v*)(wp + ct * 512);
            short8v wl = *(const short8v*)(lp + ct * 512);
            acc[ct] = __builtin_amdgcn_mfma_f32_16x16x32_bf16(xh, wh, acc[ct], 0, 0, 0);
            acc[ct] = __builtin_amdgcn_mfma_f32_16x16x32_bf16(xl, wh, acc[ct], 0, 0, 0);
            acc[ct] = __builtin_amdgcn_mfma_f32_16x16x32_bf16(xh, wl, acc[ct], 0, 0, 0);
        }
    }

    if (kh == 1) {
        #pragma unroll
        for (int ct = 0; ct < 4; ++ct) red[rt][ct][lane] = acc[ct];
    }
    __syncthreads();

    if (kh == 0) {
        #pragma unroll
        for (int ct = 0; ct < 4; ++ct) acc[ct] += red[rt][ct][lane];

        // s1/s2 (scaled by log2e): C-frag col = ct*16+l15, local row = 4g+r
        #pragma unroll
        for (int r = 0; r < 4; ++r) {
            float p1 = 0.f, p2 = 0.f;
            #pragma unroll
            for (int ct = 0; ct < 4; ++ct) {
                p1 = fmaf(acc[ct][r], a[ct * 16 + l15], p1);
                p2 = fmaf(acc[ct][r], a[64 + ct * 16 + l15], p2);
            }
            p1 += __shfl_xor(p1, 1); p2 += __shfl_xor(p2, 1);
            p1 += __shfl_xor(p1, 2); p2 += __shfl_xor(p2, 2);
            p1 += __shfl_xor(p1, 4); p2 += __shfl_xor(p2, 4);
            p1 += __shfl_xor(p1, 8); p2 += __shfl_xor(p2, 8);
            if (l15 == 0) {
                s1[row0 + g * 4 + r] = p1 * LOG2E;
                s2[row0 + g * 4 + r] = p2 * LOG2E;
            }
        }

        // transpose to [col][row] bf16 in LDS
        #pragma unroll
        for (int ct = 0; ct < 4; ++ct) {
            ushort4 pk;
            pk.x = f2bf(acc[ct][0]); pk.y = f2bf(acc[ct][1]);
            pk.z = f2bf(acc[ct][2]); pk.w = f2bf(acc[ct][3]);
            *(ushort4*)&ldsT[ct * 16 + l15][rt * 16 + g * 4] = pk;
        }
    }
    __syncthreads();

    if (kh == 0) {
        #pragma unroll
        for (int fl = 0; fl < 2; ++fl) {
            const int ft = rt * 2 + fl;
            short8v sv = *(const short8v*)&ldsT[ft * 16 + l15][g * 8];
            *(short8v*)(whtf + ((size_t)jt * 4 + ft) * 512 + (size_t)lane * 8) = sv;
        }
    }
}

// ---------------------------------------------------------------------------
// Kernel 2: fused masked-softmax attention + PV via bf16 MFMA.
// ZERO barriers in the main loop: the block's whole 128 KB whtf slice is
// staged into LDS once (global_load_lds), one __syncthreads, then each wave
// free-streams its 1024 j with register-double-buffered adj batches. The
// compiler keeps counted vmcnt (never drains to 0) across the entire loop.
// Grid 64 rowgroups x 8 jsplits = 512 blocks (1/CU via 128 KB LDS).
// ---------------------------------------------------------------------------
__global__ __launch_bounds__(512)
void gat_main(const int* __restrict__ adj, const unsigned short* __restrict__ whtf,
              const float* __restrict__ s1, const float* __restrict__ s2,
              float* __restrict__ numpart, float* __restrict__ denpart) {
    __shared__ unsigned short lds[JPB * F_OUT * 2 / 2];   // 65536 shorts = 128 KB
    const int tid  = threadIdx.x;
    const int lane = tid & 63;
    const int wv   = tid >> 6;                // 0..7: row-tile within block
    const int l15  = lane & 15, g = lane >> 4;
    const int rg   = blockIdx.x >> 3;         // 0..63 row-group (128 rows)
    const int js   = blockIdx.x & 7;          // j-split (== XCD id)
    const int rowbase = rg * 128 + wv * 16;
    const int row  = rowbase + l15;
    const int j0   = js * JPB;
    const float s1r = s1[row];                // exp2 domain

    // stage the full 128 KB whtf slice (16 rounds x 8 KB, linear dest)
    {
        const char* gsrc = (const char*)(whtf + (size_t)(j0 >> 5) * 4 * 512) + (size_t)tid * 16;
        char* ldst = (char*)&lds[0] + (size_t)tid * 16;
        #pragma unroll
        for (int r = 0; r < 16; ++r)
            __builtin_amdgcn_global_load_lds(
                (const __attribute__((address_space(1))) void*)(gsrc + r * 8192),
                (__attribute__((address_space(3))) void*)(ldst + r * 8192), 16, 0, 0);
    }

    const int*   aprow = adj + (size_t)row * N_NODES + j0 + g * 8;
    const float* s2b   = s2 + j0 + g * 8;

    __syncthreads();   // the ONLY barrier: whtf slice resident from here on

    f32x4 acc0 = {0.f, 0.f, 0.f, 0.f};
    f32x4 acc1 = acc0, acc2 = acc0, acc3 = acc0;
    float dsum = 0.f;

    i32x4 ajA[8], ajB[8];

    #define LOADBATCH(BUF, b) do { \
        _Pragma("unroll") \
        for (int _q = 0; _q < 4; ++_q) { \
            const i32x4* _ap = (const i32x4*)(aprow + (b) * 128 + _q * 32); \
            BUF[2 * _q]     = _ap[0]; \
            BUF[2 * _q + 1] = _ap[1]; \
        } \
    } while (0)

    #define CONSUME(BUF, b) do { \
        _Pragma("unroll") \
        for (int _q = 0; _q < 4; ++_q) { \
            const int _it = (b) * 4 + _q; \
            float4 sa = *(const float4*)(s2b + _it * 32); \
            float4 sb = *(const float4*)(s2b + _it * 32 + 4); \
            const unsigned short* _gb = &lds[0] + (size_t)_it * 2048 + lane * 8; \
            short8v b0 = *(const short8v*)(_gb); \
            short8v b1 = *(const short8v*)(_gb + 512); \
            short8v b2 = *(const short8v*)(_gb + 1024); \
            short8v b3 = *(const short8v*)(_gb + 1536); \
            float w0, w1, w2, w3, w4, w5, w6, w7; \
            { float e, ex; \
              e = s1r + sa.x; e = fmaxf(e, 0.2f * e); ex = __builtin_amdgcn_exp2f(e); \
              w0 = (BUF[2*_q][0] > 0) ? ex : 0.f; dsum += w0; \
              e = s1r + sa.y; e = fmaxf(e, 0.2f * e); ex = __builtin_amdgcn_exp2f(e); \
              w1 = (BUF[2*_q][1] > 0) ? ex : 0.f; dsum += w1; \
              e = s1r + sa.z; e = fmaxf(e, 0.2f * e); ex = __builtin_amdgcn_exp2f(e); \
              w2 = (BUF[2*_q][2] > 0) ? ex : 0.f; dsum += w2; \
              e = s1r + sa.w; e = fmaxf(e, 0.2f * e); ex = __builtin_amdgcn_exp2f(e); \
              w3 = (BUF[2*_q][3] > 0) ? ex : 0.f; dsum += w3; \
              e = s1r + sb.x; e = fmaxf(e, 0.2f * e); ex = __builtin_amdgcn_exp2f(e); \
              w4 = (BUF[2*_q+1][0] > 0) ? ex : 0.f; dsum += w4; \
              e = s1r + sb.y; e = fmaxf(e, 0.2f * e); ex = __builtin_amdgcn_exp2f(e); \
              w5 = (BUF[2*_q+1][1] > 0) ? ex : 0.f; dsum += w5; \
              e = s1r + sb.z; e = fmaxf(e, 0.2f * e); ex = __builtin_amdgcn_exp2f(e); \
              w6 = (BUF[2*_q+1][2] > 0) ? ex : 0.f; dsum += w6; \
              e = s1r + sb.w; e = fmaxf(e, 0.2f * e); ex = __builtin_amdgcn_exp2f(e); \
              w7 = (BUF[2*_q+1][3] > 0) ? ex : 0.f; dsum += w7; } \
            u32x4 au; \
            au[0] = cvt_pk_bf16(w0, w1); \
            au[1] = cvt_pk_bf16(w2, w3); \
            au[2] = cvt_pk_bf16(w4, w5); \
            au[3] = cvt_pk_bf16(w6, w7); \
            short8v afrag = __builtin_bit_cast(short8v, au); \
            acc0 = __builtin_amdgcn_mfma_f32_16x16x32_bf16(afrag, b0, acc0, 0, 0, 0); \
            acc1 = __builtin_amdgcn_mfma_f32_16x16x32_bf16(afrag, b1, acc1, 0, 0, 0); \
            acc2 = __builtin_amdgcn_mfma_f32_16x16x32_bf16(afrag, b2, acc2, 0, 0, 0); \
            acc3 = __builtin_amdgcn_mfma_f32_16x16x32_bf16(afrag, b3, acc3, 0, 0, 0); \
        } \
    } while (0)

    // software-pipelined, fully static: 8 batches of 128 j, A/B reg dbuf
    LOADBATCH(ajA, 0);
    #pragma unroll
    for (int bb = 0; bb < 4; ++bb) {
        LOADBATCH(ajB, 2 * bb + 1);
        CONSUME(ajA, 2 * bb);
        if (bb < 3) LOADBATCH(ajA, 2 * bb + 2);
        CONSUME(ajB, 2 * bb + 1);
    }
    #undef LOADBATCH
    #undef CONSUME

    // denominator: combine the 4 k-groups (same l15)
    dsum += __shfl_xor(dsum, 16);
    dsum += __shfl_xor(dsum, 32);
    if (lane < 16) denpart[(size_t)js * N_NODES + rowbase + lane] = dsum;

    // partial numerators: C-frag col = l15 (f = ct*16+l15), local row = g*4+r
    float* np = numpart + ((size_t)js * N_NODES + rowbase) * F_OUT;
    #pragma unroll
    for (int r = 0; r < 4; ++r) {
        const int ro = (g * 4 + r) * F_OUT;
        np[ro +  0 + l15] = acc0[r];
        np[ro + 16 + l15] = acc1[r];
        np[ro + 32 + l15] = acc2[r];
        np[ro + 48 + l15] = acc3[r];
    }
}

// ---------------------------------------------------------------------------
// Kernel 3: combine j-split partials, normalize, ELU.
// ---------------------------------------------------------------------------
__global__ __launch_bounds__(256)
void gat_combine(const float* __restrict__ numpart, const float* __restrict__ denpart,
                 float* __restrict__ out) {
    const int idx = blockIdx.x * 256 + threadIdx.x;   // 0..524287
    const int r = idx >> 6;
    float num = 0.f, den = 0.f;
    #pragma unroll
    for (int c = 0; c < JSPLIT; ++c) {
        num += numpart[(size_t)c * N_NODES * F_OUT + idx];
        den += denpart[(size_t)c * N_NODES + r];
    }
    float h = num / den;
    out[idx] = h > 0.f ? h : __expf(h) - 1.f;
}

extern "C" void kernel_launch(void* const* d_in, const int* in_sizes, int n_in,
                              void* d_out, int out_size, void* d_ws, size_t ws_size,
                              hipStream_t stream) {
    const float* x      = (const float*)d_in[0];
    const int*   adj    = (const int*)d_in[1];
    const float* weight = (const float*)d_in[2];
    const float* a      = (const float*)d_in[3];
    float* out = (float*)d_out;

    // ws: whtf 1MB | s1 32KB | s2 32KB | whf 64KB | wlf 64KB | numpart 16MB | denpart 256KB
    char* ws = (char*)d_ws;
    unsigned short* whtf = (unsigned short*)ws;
    float* s1            = (float*)(ws + 1048576);
    float* s2            = (float*)(ws + 1048576 + 32768);
    unsigned short* whf  = (unsigned short*)(ws + 1048576 + 65536);
    unsigned short* wlf  = (unsigned short*)(ws + 1048576 + 131072);
    float* numpart       = (float*)(ws + 1245184);
    float* denpart       = (float*)(ws + 1245184 + 16777216);

    gat_wconv<<<16, 256, 0, stream>>>(weight, whf, wlf);
    gat_prep<<<N_NODES / 32, 256, 0, stream>>>(x, whf, wlf, a, whtf, s1, s2);
    gat_main<<<64 * JSPLIT, 512, 0, stream>>>(adj, whtf, s1, s2, numpart, denpart);
    gat_combine<<<N_NODES * F_OUT / 256, 256, 0, stream>>>(numpart, denpart, out);
}

// Round 11
// 86.243 us; speedup vs baseline: 1.1732x; 1.1363x over previous
//
#include <hip/hip_runtime.h>
#include <hip/hip_bf16.h>
#include <cstdint>
#include <cstddef>

#define N_NODES 8192
#define F_IN 512
#define F_OUT 64
#define LOG2E 1.44269504f

#define JSPLIT 8
#define JPB (N_NODES / JSPLIT)   // 1024 j per block
#define JC 256                   // j per staged chunk (32 KB LDS)
#define NCHUNK (JPB / JC)        // 4

typedef __attribute__((ext_vector_type(8))) short short8v;  // 8 bf16 = 4 VGPRs
typedef __attribute__((ext_vector_type(4))) float f32x4;
typedef __attribute__((ext_vector_type(4))) int i32x4;
typedef __attribute__((ext_vector_type(4))) unsigned int u32x4;

static __device__ __forceinline__ unsigned short f2bf(float f) {
    union { float f; unsigned u; } v; v.f = f;
    unsigned u = v.u + 0x7FFFu + ((v.u >> 16) & 1u);   // RNE
    return (unsigned short)(u >> 16);
}
static __device__ __forceinline__ float bf2f(unsigned short b) {
    union { unsigned u; float f; } v; v.u = ((unsigned)b) << 16;
    return v.f;
}
static __device__ __forceinline__ unsigned cvt_pk_bf16(float lo, float hi) {
    unsigned r;
    asm("v_cvt_pk_bf16_f32 %0, %1, %2" : "=v"(r) : "v"(lo), "v"(hi));
    return r;
}

// ---------------------------------------------------------------------------
// Kernel 0: W (512x64 f32) -> fragment-ordered bf16 hi/lo buffers.
// ---------------------------------------------------------------------------
__global__ __launch_bounds__(256)
void gat_wconv(const float* __restrict__ W, unsigned short* __restrict__ whf,
               unsigned short* __restrict__ wlf) {
    const int t = blockIdx.x * 256 + threadIdx.x;   // 0..4095
    const int tile = t >> 6, lane = t & 63;
    const int kt = tile >> 2, ct = tile & 3;
    const int k0 = kt * 32 + ((lane >> 4) << 3);
    const int c  = ct * 16 + (lane & 15);
    short8v h, l;
    #pragma unroll
    for (int i = 0; i < 8; ++i) {
        float v = W[(size_t)(k0 + i) * F_OUT + c];
        unsigned short hb = f2bf(v);
        h[i] = (short)hb;
        l[i] = (short)f2bf(v - bf2f(hb));
    }
    const size_t dst = (size_t)tile * 512 + (size_t)lane * 8;
    *(short8v*)(whf + dst) = h;
    *(short8v*)(wlf + dst) = l;
}

// ---------------------------------------------------------------------------
// Kernel 1: Wh = x@W via bf16 hi/lo split MFMA, K split 2-way across wave
// pairs (256 thr = 4 waves: rt = wv&1 row-tile, kh = wv>>1 K-half).
// All 8 kt x-loads batched. LDS-reduce K-halves. R5-proven version.
// whtf[jt*4+ft][lane*8+i] = bf16(Wh[jt*32 + 8*(lane>>4) + i][ft*16 + (lane&15)])
// ---------------------------------------------------------------------------
__global__ __launch_bounds__(256)
void gat_prep(const float* __restrict__ x, const unsigned short* __restrict__ whf,
              const unsigned short* __restrict__ wlf, const float* __restrict__ a,
              unsigned short* __restrict__ whtf,
              float* __restrict__ s1, float* __restrict__ s2) {
    __shared__ f32x4 red[2][4][64];           // 8 KB K-half partials
    __shared__ unsigned short ldsT[64][40];   // [col][row], 80B rows
    const int tid = threadIdx.x;
    const int lane = tid & 63;
    const int wv = tid >> 6;                  // 0..3
    const int rt = wv & 1;                    // row-tile
    const int kh = wv >> 1;                   // K-half
    const int l15 = lane & 15, g = lane >> 4;
    const int jt = blockIdx.x;                // jtile 0..255
    const int row0 = jt * 32 + rt * 16;

    f32x4 acc[4] = {{0.f,0.f,0.f,0.f},{0.f,0.f,0.f,0.f},{0.f,0.f,0.f,0.f},{0.f,0.f,0.f,0.f}};

    // batch all 8 kt loads for this K-half (16 dwordx4 in flight)
    const float* xp = x + (size_t)(row0 + l15) * F_IN + kh * 256 + g * 8;
    float4 v[16];
    #pragma unroll
    for (int q = 0; q < 8; ++q) {
        v[2 * q]     = *(const float4*)(xp + q * 32);
        v[2 * q + 1] = *(const float4*)(xp + q * 32 + 4);
    }
    #pragma unroll
    for (int q = 0; q < 8; ++q) {
        const int kt = kh * 8 + q;
        float vv[8] = {v[2*q].x, v[2*q].y, v[2*q].z, v[2*q].w,
                       v[2*q+1].x, v[2*q+1].y, v[2*q+1].z, v[2*q+1].w};
        short8v xh, xl;
        #pragma unroll
        for (int i = 0; i < 8; ++i) {
            unsigned short hb = f2bf(vv[i]);
            xh[i] = (short)hb;
            xl[i] = (short)f2bf(vv[i] - bf2f(hb));
        }
        const unsigned short* wp = whf + (size_t)(kt * 4) * 512 + (size_t)lane * 8;
        const unsigned short* lp = wlf + (size_t)(kt * 4) * 512 + (size_t)lane * 8;
        #pragma unroll
        for (int ct = 0; ct < 4; ++ct) {
            short8v wh = *(const short8v*)(wp + ct * 512);
            short8v wl = *(const short8v*)(lp + ct * 512);
            acc[ct] = __builtin_amdgcn_mfma_f32_16x16x32_bf16(xh, wh, acc[ct], 0, 0, 0);
            acc[ct] = __builtin_amdgcn_mfma_f32_16x16x32_bf16(xl, wh, acc[ct], 0, 0, 0);
            acc[ct] = __builtin_amdgcn_mfma_f32_16x16x32_bf16(xh, wl, acc[ct], 0, 0, 0);
        }
    }

    if (kh == 1) {
        #pragma unroll
        for (int ct = 0; ct < 4; ++ct) red[rt][ct][lane] = acc[ct];
    }
    __syncthreads();

    if (kh == 0) {
        #pragma unroll
        for (int ct = 0; ct < 4; ++ct) acc[ct] += red[rt][ct][lane];

        // s1/s2 (scaled by log2e): C-frag col = ct*16+l15, local row = 4g+r
        #pragma unroll
        for (int r = 0; r < 4; ++r) {
            float p1 = 0.f, p2 = 0.f;
            #pragma unroll
            for (int ct = 0; ct < 4; ++ct) {
                p1 = fmaf(acc[ct][r], a[ct * 16 + l15], p1);
                p2 = fmaf(acc[ct][r], a[64 + ct * 16 + l15], p2);
            }
            p1 += __shfl_xor(p1, 1); p2 += __shfl_xor(p2, 1);
            p1 += __shfl_xor(p1, 2); p2 += __shfl_xor(p2, 2);
            p1 += __shfl_xor(p1, 4); p2 += __shfl_xor(p2, 4);
            p1 += __shfl_xor(p1, 8); p2 += __shfl_xor(p2, 8);
            if (l15 == 0) {
                s1[row0 + g * 4 + r] = p1 * LOG2E;
                s2[row0 + g * 4 + r] = p2 * LOG2E;
            }
        }

        // transpose to [col][row] bf16 in LDS
        #pragma unroll
        for (int ct = 0; ct < 4; ++ct) {
            ushort4 pk;
            pk.x = f2bf(acc[ct][0]); pk.y = f2bf(acc[ct][1]);
            pk.z = f2bf(acc[ct][2]); pk.w = f2bf(acc[ct][3]);
            *(ushort4*)&ldsT[ct * 16 + l15][rt * 16 + g * 4] = pk;
        }
    }
    __syncthreads();

    if (kh == 0) {
        #pragma unroll
        for (int fl = 0; fl < 2; ++fl) {
            const int ft = rt * 2 + fl;
            short8v sv = *(const short8v*)&ldsT[ft * 16 + l15][g * 8];
            *(short8v*)(whtf + ((size_t)jt * 4 + ft) * 512 + (size_t)lane * 8) = sv;
        }
    }
}

// ---------------------------------------------------------------------------
// Kernel 2: fused masked-softmax attention + PV via bf16 MFMA.
// Grid 64 rowgroups x 8 jsplits = 512 blocks (2/CU, 4 waves/SIMD).
// 128 rows x 1024 j per block; 32 KB whtf chunks double-buffered in LDS.
// adj loads batched 4 iterations deep (8 dwordx4 in flight per wave).
// ---------------------------------------------------------------------------
__global__ __launch_bounds__(512)
void gat_main(const int* __restrict__ adj, const unsigned short* __restrict__ whtf,
              const float* __restrict__ s1, const float* __restrict__ s2,
              float* __restrict__ numpart, float* __restrict__ denpart) {
    __shared__ unsigned short lds[2][JC * F_OUT];   // 2 x 32 KB
    const int tid  = threadIdx.x;
    const int lane = tid & 63;
    const int wv   = tid >> 6;                // 0..7: row-tile within block
    const int l15  = lane & 15, g = lane >> 4;
    const int rg   = blockIdx.x >> 3;         // 0..63 row-group (128 rows)
    const int js   = blockIdx.x & 7;          // j-split (== XCD id: L2-resident whtf slice)
    const int rowbase = rg * 128 + wv * 16;
    const int row  = rowbase + l15;
    const int j0   = js * JPB;
    const float s1r = s1[row];                // exp2 domain

    const char* gbase = (const char*)whtf + (size_t)j0 * 128;   // 128 B per j column
    const int*   aprow = adj + (size_t)row * N_NODES + j0 + g * 8;
    const float* s2b   = s2 + j0 + g * 8;

    f32x4 acc0 = {0.f, 0.f, 0.f, 0.f};
    f32x4 acc1 = acc0, acc2 = acc0, acc3 = acc0;
    float dsum = 0.f;

    #define STAGE(ch, buf) do { \
        const char* _g = gbase + (size_t)(ch) * 32768 + (size_t)tid * 16; \
        char* _l = (char*)&lds[buf][0] + (size_t)wv * 1024; \
        _Pragma("unroll") \
        for (int _i = 0; _i < 4; ++_i) \
            __builtin_amdgcn_global_load_lds( \
                (const __attribute__((address_space(1))) void*)(_g + _i * 8192), \
                (__attribute__((address_space(3))) void*)(_l + _i * 8192), 16, 0, 0); \
    } while (0)

    STAGE(0, 0);
    __syncthreads();

    for (int ch = 0; ch < NCHUNK; ++ch) {
        const int cur = ch & 1;
        if (ch < NCHUNK - 1) STAGE(ch + 1, cur ^ 1);

        const unsigned short* lbuf = &lds[cur][0];
        #pragma unroll
        for (int itg = 0; itg < 2; ++itg) {
            // batch 4 iterations of adj loads (8 dwordx4 in flight)
            i32x4 aj[8];
            #pragma unroll
            for (int q = 0; q < 4; ++q) {
                const i32x4* ap = (const i32x4*)(aprow + ch * JC + itg * 128 + q * 32);
                aj[2 * q]     = ap[0];
                aj[2 * q + 1] = ap[1];
            }
            #pragma unroll
            for (int q = 0; q < 4; ++q) {
                const int it = itg * 4 + q;
                const int jw = ch * JC + it * 32;
                float4 sa = *(const float4*)(s2b + jw);
                float4 sb = *(const float4*)(s2b + jw + 4);

                short8v b0 = *(const short8v*)(lbuf + (it * 4 + 0) * 512 + lane * 8);
                short8v b1 = *(const short8v*)(lbuf + (it * 4 + 1) * 512 + lane * 8);
                short8v b2 = *(const short8v*)(lbuf + (it * 4 + 2) * 512 + lane * 8);
                short8v b3 = *(const short8v*)(lbuf + (it * 4 + 3) * 512 + lane * 8);

                float w0, w1, w2, w3, w4, w5, w6, w7;
                #define GAT_EL(wvar, ajv, s2v) do { \
                    float e = s1r + (s2v); e = fmaxf(e, 0.2f * e); \
                    float ex = __builtin_amdgcn_exp2f(e); \
                    wvar = ((ajv) > 0) ? ex : 0.f; dsum += wvar; } while (0);
                GAT_EL(w0, aj[2*q][0], sa.x) GAT_EL(w1, aj[2*q][1], sa.y)
                GAT_EL(w2, aj[2*q][2], sa.z) GAT_EL(w3, aj[2*q][3], sa.w)
                GAT_EL(w4, aj[2*q+1][0], sb.x) GAT_EL(w5, aj[2*q+1][1], sb.y)
                GAT_EL(w6, aj[2*q+1][2], sb.z) GAT_EL(w7, aj[2*q+1][3], sb.w)
                #undef GAT_EL

                u32x4 au;
                au[0] = cvt_pk_bf16(w0, w1);
                au[1] = cvt_pk_bf16(w2, w3);
                au[2] = cvt_pk_bf16(w4, w5);
                au[3] = cvt_pk_bf16(w6, w7);
                short8v afrag = __builtin_bit_cast(short8v, au);

                acc0 = __builtin_amdgcn_mfma_f32_16x16x32_bf16(afrag, b0, acc0, 0, 0, 0);
                acc1 = __builtin_amdgcn_mfma_f32_16x16x32_bf16(afrag, b1, acc1, 0, 0, 0);
                acc2 = __builtin_amdgcn_mfma_f32_16x16x32_bf16(afrag, b2, acc2, 0, 0, 0);
                acc3 = __builtin_amdgcn_mfma_f32_16x16x32_bf16(afrag, b3, acc3, 0, 0, 0);
            }
        }
        __syncthreads();   // drains stage loads AND fences buffer reuse
    }
    #undef STAGE

    // denominator: combine the 4 k-groups (same l15)
    dsum += __shfl_xor(dsum, 16);
    dsum += __shfl_xor(dsum, 32);
    if (lane < 16) denpart[(size_t)js * N_NODES + rowbase + lane] = dsum;

    // partial numerators: C-frag col = l15 (f = ft*16+l15), local row = g*4+r
    float* np = numpart + ((size_t)js * N_NODES + rowbase) * F_OUT;
    #pragma unroll
    for (int r = 0; r < 4; ++r) {
        const int ro = (g * 4 + r) * F_OUT;
        np[ro +  0 + l15] = acc0[r];
        np[ro + 16 + l15] = acc1[r];
        np[ro + 32 + l15] = acc2[r];
        np[ro + 48 + l15] = acc3[r];
    }
}

// ---------------------------------------------------------------------------
// Kernel 3: combine j-split partials, normalize, ELU.
// ---------------------------------------------------------------------------
__global__ __launch_bounds__(256)
void gat_combine(const float* __restrict__ numpart, const float* __restrict__ denpart,
                 float* __restrict__ out) {
    const int idx = blockIdx.x * 256 + threadIdx.x;   // 0..524287
    const int r = idx >> 6;
    float num = 0.f, den = 0.f;
    #pragma unroll
    for (int c = 0; c < JSPLIT; ++c) {
        num += numpart[(size_t)c * N_NODES * F_OUT + idx];
        den += denpart[(size_t)c * N_NODES + r];
    }
    float h = num / den;
    out[idx] = h > 0.f ? h : __expf(h) - 1.f;
}

extern "C" void kernel_launch(void* const* d_in, const int* in_sizes, int n_in,
                              void* d_out, int out_size, void* d_ws, size_t ws_size,
                              hipStream_t stream) {
    const float* x      = (const float*)d_in[0];
    const int*   adj    = (const int*)d_in[1];
    const float* weight = (const float*)d_in[2];
    const float* a      = (const float*)d_in[3];
    float* out = (float*)d_out;

    // ws: whtf 1MB | s1 32KB | s2 32KB | whf 64KB | wlf 64KB | numpart 16MB | denpart 256KB
    char* ws = (char*)d_ws;
    unsigned short* whtf = (unsigned short*)ws;
    float* s1            = (float*)(ws + 1048576);
    float* s2            = (float*)(ws + 1048576 + 32768);
    unsigned short* whf  = (unsigned short*)(ws + 1048576 + 65536);
    unsigned short* wlf  = (unsigned short*)(ws + 1048576 + 131072);
    float* numpart       = (float*)(ws + 1048576 + 196608);
    float* denpart       = (float*)(ws + 1048576 + 196608 + (size_t)JSPLIT * N_NODES * F_OUT * 4);

    gat_wconv<<<16, 256, 0, stream>>>(weight, whf, wlf);
    gat_prep<<<N_NODES / 32, 256, 0, stream>>>(x, whf, wlf, a, whtf, s1, s2);
    gat_main<<<64 * JSPLIT, 512, 0, stream>>>(adj, whtf, s1, s2, numpart, denpart);
    gat_combine<<<N_NODES * F_OUT / 256, 256, 0, stream>>>(numpart, denpart, out);
}